// Round 1
// baseline (145.174 us; speedup 1.0000x reference)
//
#include <hip/hip_runtime.h>

typedef __attribute__((ext_vector_type(8))) short short8v;
typedef __attribute__((ext_vector_type(4))) float f32x4;

// ---------- helpers ----------
__device__ inline unsigned short f2b(float f) {
    unsigned u = __builtin_bit_cast(unsigned, f);
    unsigned r = u + 0x7fffu + ((u >> 16) & 1u);
    return (unsigned short)(r >> 16);
}
__device__ inline float b2f(unsigned short us) {
    return __builtin_bit_cast(float, ((unsigned)us) << 16);
}
__device__ inline void gload16(const void* g, void* l) {
    __builtin_amdgcn_global_load_lds(
        (const __attribute__((address_space(1))) void*)g,
        (__attribute__((address_space(3))) void*)l, 16, 0, 0);
}

// ---------- prep: f32->bf16 conversion + per-token seg/j/destrow ----------
__global__ __launch_bounds__(256)
void prep_kernel(const float* __restrict__ x, const float* __restrict__ wkv,
                 const float* __restrict__ wq, const float* __restrict__ wp,
                 const float* __restrict__ buf, const int* __restrict__ sl,
                 short* __restrict__ dst, int* __restrict__ jj,
                 int* __restrict__ destrow,
                 long n0, long n1, long n2, long n3, long n4,
                 int T, int Bn, int MAXL)
{
    long gid = (long)blockIdx.x * blockDim.x + threadIdx.x;
    long e = gid * 8;
    if (e < n4) {
        const float* s; long off;
        if (e < n0)      { s = x;   off = e; }
        else if (e < n1) { s = wkv; off = e - n0; }
        else if (e < n2) { s = wq;  off = e - n1; }
        else if (e < n3) { s = wp;  off = e - n2; }
        else             { s = buf; off = e - n3; }
        float4 a = *(const float4*)(s + off);
        float4 b = *(const float4*)(s + off + 4);
        short8v o;
        o[0] = (short)f2b(a.x); o[1] = (short)f2b(a.y);
        o[2] = (short)f2b(a.z); o[3] = (short)f2b(a.w);
        o[4] = (short)f2b(b.x); o[5] = (short)f2b(b.y);
        o[6] = (short)f2b(b.z); o[7] = (short)f2b(b.w);
        *(short8v*)(dst + e) = o;
    }
    if (gid < T) {
        int start = 0, seg = 0, jloc = 0;
        for (int i = 0; i < Bn; ++i) {
            int len = sl[i];
            if (gid >= start && gid < start + len) { seg = i; jloc = (int)gid - start; }
            start += len;
        }
        jj[gid] = jloc;
        destrow[gid] = seg * MAXL + jloc;
    }
}

// ---------- bf16 GEMM: C[M,N] = A[M,K] @ B[N,K]^T + bias ----------
// MODE 0: write bf16 row-major C. MODE 1: write f32 rows scattered via destrow.
template<int MODE>
__global__ __launch_bounds__(256)
void gemm_bt(const short* __restrict__ A, const short* __restrict__ Bm,
             const float* __restrict__ bias,
             short* __restrict__ Cb, float* __restrict__ Cf,
             const int* __restrict__ destrow,
             int M, int N, int Kd)
{
    __shared__ short lA[128 * 32];
    __shared__ short lB[128 * 32];
    int nb = N >> 7;
    int bid = blockIdx.x;
    int m0 = (bid / nb) << 7, n0 = (bid % nb) << 7;
    int tid = threadIdx.x;
    int lane = tid & 63, wid = tid >> 6;
    int wm = wid >> 1, wn = wid & 1;
    f32x4 acc[4][4];
    #pragma unroll
    for (int i = 0; i < 4; ++i)
        #pragma unroll
        for (int j2 = 0; j2 < 4; ++j2)
            acc[i][j2] = (f32x4)(0.f);

    const int srow = tid >> 2;
    const int scol = (tid & 3) * 8;
    const short* ga = A + (size_t)(m0 + srow) * Kd + scol;
    const short* gb = Bm + (size_t)(n0 + srow) * Kd + scol;
    short* la0 = &lA[tid * 8];
    short* la1 = &lA[64 * 32 + tid * 8];
    short* lb0 = &lB[tid * 8];
    short* lb1 = &lB[64 * 32 + tid * 8];

    int r = lane & 15, kc = (lane >> 4) * 8;

    for (int k0 = 0; k0 < Kd; k0 += 32) {
        __syncthreads();
        gload16(ga + k0, la0);
        gload16(ga + (size_t)64 * Kd + k0, la1);
        gload16(gb + k0, lb0);
        gload16(gb + (size_t)64 * Kd + k0, lb1);
        __syncthreads();
        short8v af[4], bf[4];
        #pragma unroll
        for (int f = 0; f < 4; ++f)
            af[f] = *(const short8v*)&lA[(wm * 64 + f * 16 + r) * 32 + kc];
        #pragma unroll
        for (int f = 0; f < 4; ++f)
            bf[f] = *(const short8v*)&lB[(wn * 64 + f * 16 + r) * 32 + kc];
        #pragma unroll
        for (int i = 0; i < 4; ++i)
            #pragma unroll
            for (int j2 = 0; j2 < 4; ++j2)
                acc[i][j2] = __builtin_amdgcn_mfma_f32_16x16x32_bf16(
                    af[i], bf[j2], acc[i][j2], 0, 0, 0);
    }

    int cr = (lane >> 4) * 4;
    int cc = lane & 15;
    #pragma unroll
    for (int j2 = 0; j2 < 4; ++j2) {
        int col = n0 + wn * 64 + j2 * 16 + cc;
        float bv = bias[col];
        #pragma unroll
        for (int i = 0; i < 4; ++i) {
            int rowb = m0 + wm * 64 + i * 16 + cr;
            #pragma unroll
            for (int rr = 0; rr < 4; ++rr) {
                float v = acc[i][j2][rr] + bv;
                int row = rowb + rr;
                if (MODE == 0) {
                    Cb[(size_t)row * N + col] = (short)f2b(v);
                } else {
                    int dr = destrow[row];
                    Cf[(size_t)dr * N + col] = v;
                }
            }
        }
    }
}

// ---------- windowed attention ----------
// 1 wave per token; lanes: g = lane>>5 selects head of pair, c = lane&31 = window pos.
__global__ __launch_bounds__(256)
void attn_kernel(const short* __restrict__ kv, const short* __restrict__ q,
                 const short* __restrict__ bufb, const int* __restrict__ jj,
                 short* __restrict__ o, int T)
{
    __shared__ short qs[4][512];
    int wid = threadIdx.x >> 6, lane = threadIdx.x & 63;
    int nbb = gridDim.x >> 3;
    int b = blockIdx.x;
    int sb = (b & 7) * nbb + (b >> 3);   // XCD-contiguous token blocks
    int t = sb * 4 + wid;

    *(short8v*)&qs[wid][lane * 8] = *(const short8v*)&q[(size_t)t * 512 + lane * 8];
    __syncthreads();

    int j = jj[t];
    int g = lane >> 5, c = lane & 31;
    const short* kr = (j >= c) ? (kv + (size_t)(t - c) * 1536)
                               : (bufb + (size_t)(31 + j - c) * 1536);

    for (int hp = 0; hp < 8; ++hp) {
        int h = hp * 2 + g;
        const short* kp = kr + h * 32;
        float acc = 0.f;
        #pragma unroll
        for (int dc = 0; dc < 4; ++dc) {
            short8v kk = *(const short8v*)(kp + dc * 8);
            short8v qq = *(const short8v*)&qs[wid][h * 32 + dc * 8];
            #pragma unroll
            for (int e2 = 0; e2 < 8; ++e2)
                acc += b2f((unsigned short)kk[e2]) * b2f((unsigned short)qq[e2]);
        }
        float logit = acc * 0.17677669529663687f;
        float mx = logit;
        #pragma unroll
        for (int mk = 16; mk >= 1; mk >>= 1)
            mx = fmaxf(mx, __shfl_xor(mx, mk, 64));
        float p = __expf(logit - mx);
        float s = p;
        #pragma unroll
        for (int mk = 16; mk >= 1; mk >>= 1)
            s += __shfl_xor(s, mk, 64);
        p = p / s;

        float o0 = 0.f, o1 = 0.f;
        int d0 = 2 * c;
        #pragma unroll 4
        for (int c2 = 0; c2 < 32; ++c2) {
            float pc = __shfl(p, (g << 5) | c2, 64);
            const short* vr = ((j >= c2) ? (kv + (size_t)(t - c2) * 1536)
                                         : (bufb + (size_t)(31 + j - c2) * 1536))
                              + 512 + h * 64 + d0;
            unsigned vv = *(const unsigned*)vr;
            o0 += pc * b2f((unsigned short)(vv & 0xffffu));
            o1 += pc * b2f((unsigned short)(vv >> 16));
        }
        unsigned ov = ((unsigned)f2b(o1) << 16) | (unsigned)f2b(o0);
        *(unsigned*)&o[(size_t)t * 1024 + h * 64 + d0] = ov;
    }
}

// ---------- host ----------
extern "C" void kernel_launch(void* const* d_in, const int* in_sizes, int n_in,
                              void* d_out, int out_size, void* d_ws, size_t ws_size,
                              hipStream_t stream)
{
    const float* x      = (const float*)d_in[0];
    const float* Wkv    = (const float*)d_in[1];
    const float* bkv    = (const float*)d_in[2];
    const float* Wq     = (const float*)d_in[3];
    const float* bq     = (const float*)d_in[4];
    const float* Wp     = (const float*)d_in[5];
    const float* bp     = (const float*)d_in[6];
    const float* buffer = (const float*)d_in[7];
    const int*   sl     = (const int*)d_in[8];

    int E  = in_sizes[6];          // 1024
    int Kc = in_sizes[4];          // 512
    int T  = in_sizes[0] / E;      // 4096
    int Bn = in_sizes[8];          // 8
    int EK = E + Kc;               // 1536
    int MAXL = out_size / (Bn * E);

    size_t nX = (size_t)T * E, nWkv = (size_t)EK * E, nWq = (size_t)Kc * E;
    size_t nWp = (size_t)E * E, nBuf = (size_t)in_sizes[7];

    short* xb   = (short*)d_ws;
    short* wkvb = xb + nX;
    short* wqb  = wkvb + nWkv;
    short* wpb  = wqb + nWq;
    short* bufb = wpb + nWp;
    short* kvb  = bufb + nBuf;
    short* qb   = kvb + (size_t)T * EK;
    short* ob   = qb + (size_t)T * Kc;
    int*   jj      = (int*)(ob + (size_t)T * E);
    int*   destrow = jj + T;

    float* y = (float*)d_out;
    hipMemsetAsync(d_out, 0, (size_t)out_size * sizeof(float), stream);

    long n0 = (long)nX, n1 = n0 + (long)nWkv, n2 = n1 + (long)nWq;
    long n3 = n2 + (long)nWp, n4 = n3 + (long)nBuf;
    int prep_blocks = (int)((n4 / 8 + 255) / 256);
    prep_kernel<<<prep_blocks, 256, 0, stream>>>(
        x, Wkv, Wq, Wp, buffer, sl, xb, jj, destrow,
        n0, n1, n2, n3, n4, T, Bn, MAXL);

    gemm_bt<0><<<(T / 128) * (EK / 128), 256, 0, stream>>>(
        xb, wkvb, bkv, kvb, nullptr, nullptr, T, EK, E);
    gemm_bt<0><<<(T / 128) * (Kc / 128), 256, 0, stream>>>(
        xb, wqb, bq, qb, nullptr, nullptr, T, Kc, E);

    attn_kernel<<<T / 4, 256, 0, stream>>>(kvb, qb, bufb, jj, ob, T);

    gemm_bt<1><<<(T / 128) * (E / 128), 256, 0, stream>>>(
        ob, wpb, bp, nullptr, y, destrow, T, E, E);
}

// Round 2
// 112.749 us; speedup vs baseline: 1.2876x; 1.2876x over previous
//
#include <hip/hip_runtime.h>

typedef __attribute__((ext_vector_type(8))) short short8v;
typedef __attribute__((ext_vector_type(4))) float f32x4;

// ---------- helpers ----------
__device__ inline unsigned short f2b(float f) {
    unsigned u = __builtin_bit_cast(unsigned, f);
    unsigned r = u + 0x7fffu + ((u >> 16) & 1u);
    return (unsigned short)(r >> 16);
}
__device__ inline float blo(unsigned u) {
    return __builtin_bit_cast(float, u << 16);
}
__device__ inline float bhi(unsigned u) {
    return __builtin_bit_cast(float, u & 0xffff0000u);
}
__device__ inline void gload16(const void* g, void* l) {
    __builtin_amdgcn_global_load_lds(
        (const __attribute__((address_space(1))) void*)g,
        (__attribute__((address_space(3))) void*)l, 16, 0, 0);
}

// ---------- prep: f32->bf16 conversion + seg/j/destrow + bias concat ----------
__global__ __launch_bounds__(256)
void prep_kernel(const float* __restrict__ x, const float* __restrict__ wkv,
                 const float* __restrict__ wq, const float* __restrict__ wp,
                 const float* __restrict__ buf, const int* __restrict__ sl,
                 const float* __restrict__ bkv, const float* __restrict__ bq,
                 short* __restrict__ dst, int* __restrict__ jj,
                 int* __restrict__ destrow, float* __restrict__ biascat,
                 long n0, long n1, long n2, long n3, long n4,
                 int T, int Bn, int MAXL, int EK, int NKVQ)
{
    long gid = (long)blockIdx.x * blockDim.x + threadIdx.x;
    long e = gid * 8;
    if (e < n4) {
        const float* s; long off;
        if (e < n0)      { s = x;   off = e; }
        else if (e < n1) { s = wkv; off = e - n0; }
        else if (e < n2) { s = wq;  off = e - n1; }
        else if (e < n3) { s = wp;  off = e - n2; }
        else             { s = buf; off = e - n3; }
        float4 a = *(const float4*)(s + off);
        float4 b = *(const float4*)(s + off + 4);
        short8v o;
        o[0] = (short)f2b(a.x); o[1] = (short)f2b(a.y);
        o[2] = (short)f2b(a.z); o[3] = (short)f2b(a.w);
        o[4] = (short)f2b(b.x); o[5] = (short)f2b(b.y);
        o[6] = (short)f2b(b.z); o[7] = (short)f2b(b.w);
        *(short8v*)(dst + e) = o;
    }
    if (gid < T) {
        int start = 0, seg = 0, jloc = 0;
        for (int i = 0; i < Bn; ++i) {
            int len = sl[i];
            if (gid >= start && gid < start + len) { seg = i; jloc = (int)gid - start; }
            start += len;
        }
        jj[gid] = jloc;
        destrow[gid] = seg * MAXL + jloc;
    }
    if (gid < NKVQ) {
        biascat[gid] = (gid < EK) ? bkv[gid] : bq[gid - EK];
    }
}

// ---------- bf16 GEMM: C[M,N] = A[M,K] @ B[N,K]^T + bias ----------
// MODE 0: write bf16 row-major C. MODE 1: write f32 rows scattered via destrow.
template<int MODE>
__global__ __launch_bounds__(256)
void gemm_bt(const short* __restrict__ A, const short* __restrict__ Bm,
             const float* __restrict__ bias,
             short* __restrict__ Cb, float* __restrict__ Cf,
             const int* __restrict__ destrow,
             int M, int N, int Kd)
{
    __shared__ short lA[128 * 32];
    __shared__ short lB[128 * 32];
    int nb = N >> 7;
    int bid = blockIdx.x;
    int m0 = (bid / nb) << 7, n0 = (bid % nb) << 7;
    int tid = threadIdx.x;
    int lane = tid & 63, wid = tid >> 6;
    int wm = wid >> 1, wn = wid & 1;
    f32x4 acc[4][4];
    #pragma unroll
    for (int i = 0; i < 4; ++i)
        #pragma unroll
        for (int j2 = 0; j2 < 4; ++j2)
            acc[i][j2] = (f32x4)(0.f);

    const int srow = tid >> 2;
    const int scol = (tid & 3) * 8;
    const short* ga = A + (size_t)(m0 + srow) * Kd + scol;
    const short* gb = Bm + (size_t)(n0 + srow) * Kd + scol;
    short* la0 = &lA[tid * 8];
    short* la1 = &lA[64 * 32 + tid * 8];
    short* lb0 = &lB[tid * 8];
    short* lb1 = &lB[64 * 32 + tid * 8];

    int r = lane & 15, kc = (lane >> 4) * 8;

    for (int k0 = 0; k0 < Kd; k0 += 32) {
        __syncthreads();
        gload16(ga + k0, la0);
        gload16(ga + (size_t)64 * Kd + k0, la1);
        gload16(gb + k0, lb0);
        gload16(gb + (size_t)64 * Kd + k0, lb1);
        __syncthreads();
        short8v af[4], bf[4];
        #pragma unroll
        for (int f = 0; f < 4; ++f)
            af[f] = *(const short8v*)&lA[(wm * 64 + f * 16 + r) * 32 + kc];
        #pragma unroll
        for (int f = 0; f < 4; ++f)
            bf[f] = *(const short8v*)&lB[(wn * 64 + f * 16 + r) * 32 + kc];
        #pragma unroll
        for (int i = 0; i < 4; ++i)
            #pragma unroll
            for (int j2 = 0; j2 < 4; ++j2)
                acc[i][j2] = __builtin_amdgcn_mfma_f32_16x16x32_bf16(
                    af[i], bf[j2], acc[i][j2], 0, 0, 0);
    }

    int cr = (lane >> 4) * 4;
    int cc = lane & 15;
    #pragma unroll
    for (int j2 = 0; j2 < 4; ++j2) {
        int col = n0 + wn * 64 + j2 * 16 + cc;
        float bv = bias[col];
        #pragma unroll
        for (int i = 0; i < 4; ++i) {
            int rowb = m0 + wm * 64 + i * 16 + cr;
            #pragma unroll
            for (int rr = 0; rr < 4; ++rr) {
                float v = acc[i][j2][rr] + bv;
                int row = rowb + rr;
                if (MODE == 0) {
                    Cb[(size_t)row * N + col] = (short)f2b(v);
                } else {
                    int dr = destrow[row];
                    Cf[(size_t)dr * N + col] = v;
                }
            }
        }
    }
}

// ---------- windowed attention v2 ----------
// 1 block (4 waves) per token; wave w owns heads 4w..4w+3.
// Phase 1 (QK+softmax): lanes (g=lane>>5, c=lane&31), 2 sub-iterations cover
//   the wave's 4 heads; p stored to padded LDS ps[16][33].
// Phase 2 (PV): lanes (hl=lane>>4, dq=lane&15); vectorized 8B V loads,
//   4 independent accumulation chains. No cross-wave deps -> no barriers.
__global__ __launch_bounds__(256)
void attn2_kernel(const short* __restrict__ kvq, const short* __restrict__ bufb,
                  const int* __restrict__ jj, short* __restrict__ o, int T)
{
    __shared__ float ps[16][33];
    int b = blockIdx.x;
    int chunk = gridDim.x >> 3;
    int t = (b & 7) * chunk + (b >> 3);    // XCD-contiguous token chunks
    int tid = threadIdx.x;
    int wv = tid >> 6, lane = tid & 63;
    int j = jj[t];

    // ---- Phase 1: logits + softmax ----
    {
        int g = lane >> 5, c = lane & 31;
        const short* krow = (j >= c) ? (kvq + (size_t)(t - c) * 2048)
                                     : (bufb + (size_t)(31 + j - c) * 1536);
        const short* qrow = kvq + (size_t)t * 2048 + 1536;
        #pragma unroll
        for (int sub = 0; sub < 2; ++sub) {
            int h = wv * 4 + sub * 2 + g;
            const short* kp = krow + h * 32;
            const short* qp = qrow + h * 32;
            float acc0 = 0.f, acc1 = 0.f;
            #pragma unroll
            for (int dc = 0; dc < 2; ++dc) {
                uint4 kk = *(const uint4*)(kp + dc * 8);
                uint4 qq = *(const uint4*)(qp + dc * 8);
                const unsigned* ka = (const unsigned*)&kk;
                const unsigned* qa = (const unsigned*)&qq;
                #pragma unroll
                for (int i = 0; i < 4; ++i) {
                    acc0 = fmaf(blo(ka[i]), blo(qa[i]), acc0);
                    acc0 = fmaf(bhi(ka[i]), bhi(qa[i]), acc0);
                }
            }
            #pragma unroll
            for (int dc = 2; dc < 4; ++dc) {
                uint4 kk = *(const uint4*)(kp + dc * 8);
                uint4 qq = *(const uint4*)(qp + dc * 8);
                const unsigned* ka = (const unsigned*)&kk;
                const unsigned* qa = (const unsigned*)&qq;
                #pragma unroll
                for (int i = 0; i < 4; ++i) {
                    acc1 = fmaf(blo(ka[i]), blo(qa[i]), acc1);
                    acc1 = fmaf(bhi(ka[i]), bhi(qa[i]), acc1);
                }
            }
            float logit = (acc0 + acc1) * 0.17677669529663687f;
            float mx = logit;
            #pragma unroll
            for (int mk = 16; mk >= 1; mk >>= 1)
                mx = fmaxf(mx, __shfl_xor(mx, mk, 64));
            float p = __expf(logit - mx);
            float s = p;
            #pragma unroll
            for (int mk = 16; mk >= 1; mk >>= 1)
                s += __shfl_xor(s, mk, 64);
            ps[h][c] = p / s;
        }
    }

    // ---- Phase 2: PV (same wave reads only its own heads' ps rows) ----
    {
        int hl = lane >> 4, dq = lane & 15;
        int h = wv * 4 + hl;
        int d0 = dq * 4;
        const short* kvrow  = kvq + (size_t)t * 2048 + 512 + h * 64 + d0;
        const short* bufrow = bufb + (size_t)(31 + j) * 1536 + 512 + h * 64 + d0;
        float a0 = 0.f, a1 = 0.f, a2 = 0.f, a3 = 0.f;
        #pragma unroll 8
        for (int c2 = 0; c2 < 32; ++c2) {
            float pc = ps[h][c2];
            const short* vr = (j >= c2) ? (kvrow - (size_t)c2 * 2048)
                                        : (bufrow - (size_t)c2 * 1536);
            uint2 vv = *(const uint2*)vr;
            a0 = fmaf(pc, blo(vv.x), a0);
            a1 = fmaf(pc, bhi(vv.x), a1);
            a2 = fmaf(pc, blo(vv.y), a2);
            a3 = fmaf(pc, bhi(vv.y), a3);
        }
        unsigned w0 = ((unsigned)f2b(a1) << 16) | (unsigned)f2b(a0);
        unsigned w1 = ((unsigned)f2b(a3) << 16) | (unsigned)f2b(a2);
        uint2 ov; ov.x = w0; ov.y = w1;
        *(uint2*)&o[(size_t)t * 1024 + h * 64 + d0] = ov;
    }
}

// ---------- host ----------
extern "C" void kernel_launch(void* const* d_in, const int* in_sizes, int n_in,
                              void* d_out, int out_size, void* d_ws, size_t ws_size,
                              hipStream_t stream)
{
    const float* x      = (const float*)d_in[0];
    const float* Wkv    = (const float*)d_in[1];
    const float* bkv    = (const float*)d_in[2];
    const float* Wq     = (const float*)d_in[3];
    const float* bq     = (const float*)d_in[4];
    const float* Wp     = (const float*)d_in[5];
    const float* bp     = (const float*)d_in[6];
    const float* buffer = (const float*)d_in[7];
    const int*   sl     = (const int*)d_in[8];

    int E  = in_sizes[6];          // 1024
    int Kc = in_sizes[4];          // 512
    int T  = in_sizes[0] / E;      // 4096
    int Bn = in_sizes[8];          // 8
    int EK = E + Kc;               // 1536
    int NKVQ = EK + Kc;            // 2048
    int MAXL = out_size / (Bn * E);

    size_t nX = (size_t)T * E, nWkv = (size_t)EK * E, nWq = (size_t)Kc * E;
    size_t nWp = (size_t)E * E, nBuf = (size_t)in_sizes[7];

    short* xb    = (short*)d_ws;
    short* wkvqb = xb + nX;                 // [EK+Kc, E] contiguous (Wkv rows then Wq rows)
    short* wpb   = wkvqb + nWkv + nWq;
    short* bufb  = wpb + nWp;
    short* kvqb  = bufb + nBuf;             // [T, 2048]: cols 0..1535 kv, 1536..2047 q
    short* ob    = kvqb + (size_t)T * NKVQ;
    int*   jj      = (int*)(ob + (size_t)T * E);
    int*   destrow = jj + T;
    float* biascat = (float*)(destrow + T); // [2048]

    float* y = (float*)d_out;
    hipMemsetAsync(d_out, 0, (size_t)out_size * sizeof(float), stream);

    long n0 = (long)nX, n1 = n0 + (long)nWkv, n2 = n1 + (long)nWq;
    long n3 = n2 + (long)nWp, n4 = n3 + (long)nBuf;
    int prep_blocks = (int)((n4 / 8 + 255) / 256);
    prep_kernel<<<prep_blocks, 256, 0, stream>>>(
        x, Wkv, Wq, Wp, buffer, sl, bkv, bq, xb, jj, destrow, biascat,
        n0, n1, n2, n3, n4, T, Bn, MAXL, EK, NKVQ);

    // merged kv+q projection: [T,1024] @ [2048,1024]^T -> [T,2048]
    gemm_bt<0><<<(T / 128) * (NKVQ / 128), 256, 0, stream>>>(
        xb, wkvqb, biascat, kvqb, nullptr, nullptr, T, NKVQ, E);

    attn2_kernel<<<T, 256, 0, stream>>>(kvqb, bufb, jj, ob, T);

    gemm_bt<1><<<(T / 128) * (E / 128), 256, 0, stream>>>(
        ob, wpb, bp, nullptr, y, destrow, T, E, E);
}

// Round 3
// 108.668 us; speedup vs baseline: 1.3359x; 1.0376x over previous
//
#include <hip/hip_runtime.h>

typedef __attribute__((ext_vector_type(8))) short short8v;
typedef __attribute__((ext_vector_type(4))) float f32x4;

// ---------- helpers ----------
__device__ inline unsigned short f2b(float f) {
    unsigned u = __builtin_bit_cast(unsigned, f);
    unsigned r = u + 0x7fffu + ((u >> 16) & 1u);
    return (unsigned short)(r >> 16);
}
__device__ inline float blo(unsigned u) {
    return __builtin_bit_cast(float, u << 16);
}
__device__ inline float bhi(unsigned u) {
    return __builtin_bit_cast(float, u & 0xffff0000u);
}
__device__ inline void gload16(const void* g, void* l) {
    __builtin_amdgcn_global_load_lds(
        (const __attribute__((address_space(1))) void*)g,
        (__attribute__((address_space(3))) void*)l, 16, 0, 0);
}

// ---------- prep: f32->bf16 conversion + seg/j/destrow + bias concat ----------
__global__ __launch_bounds__(256)
void prep_kernel(const float* __restrict__ x, const float* __restrict__ wkv,
                 const float* __restrict__ wq, const float* __restrict__ wp,
                 const float* __restrict__ buf, const int* __restrict__ sl,
                 const float* __restrict__ bkv, const float* __restrict__ bq,
                 short* __restrict__ dst, int* __restrict__ jj,
                 int* __restrict__ destrow, float* __restrict__ biascat,
                 long n0, long n1, long n2, long n3, long n4,
                 int T, int Bn, int MAXL, int EK, int NKVQ)
{
    long gid = (long)blockIdx.x * blockDim.x + threadIdx.x;
    long e = gid * 8;
    if (e < n4) {
        const float* s; long off;
        if (e < n0)      { s = x;   off = e; }
        else if (e < n1) { s = wkv; off = e - n0; }
        else if (e < n2) { s = wq;  off = e - n1; }
        else if (e < n3) { s = wp;  off = e - n2; }
        else             { s = buf; off = e - n3; }
        float4 a = *(const float4*)(s + off);
        float4 b = *(const float4*)(s + off + 4);
        short8v o;
        o[0] = (short)f2b(a.x); o[1] = (short)f2b(a.y);
        o[2] = (short)f2b(a.z); o[3] = (short)f2b(a.w);
        o[4] = (short)f2b(b.x); o[5] = (short)f2b(b.y);
        o[6] = (short)f2b(b.z); o[7] = (short)f2b(b.w);
        *(short8v*)(dst + e) = o;
    }
    if (gid < T) {
        int start = 0, seg = 0, jloc = 0;
        for (int i = 0; i < Bn; ++i) {
            int len = sl[i];
            if (gid >= start && gid < start + len) { seg = i; jloc = (int)gid - start; }
            start += len;
        }
        jj[gid] = jloc;
        destrow[gid] = seg * MAXL + jloc;
    }
    if (gid < NKVQ) {
        biascat[gid] = (gid < EK) ? bkv[gid] : bq[gid - EK];
    }
}

// ---------- zero only the padding rows of y ----------
__global__ __launch_bounds__(256)
void padzero_kernel(float* __restrict__ y, const int* __restrict__ sl,
                    int MAXL, int E)
{
    int row = blockIdx.x;
    int seg = row / MAXL, pos = row - seg * MAXL;
    if (pos < sl[seg]) return;
    float4 z = {0.f, 0.f, 0.f, 0.f};
    *(float4*)&y[(size_t)row * E + threadIdx.x * 4] = z;
}

// ---------- bf16 GEMM: C[M,N] = A[M,K] @ B[N,K]^T + bias ----------
// MODE 0: write bf16 row-major C. MODE 1: write f32 rows scattered via destrow.
template<int MODE>
__global__ __launch_bounds__(256)
void gemm_bt(const short* __restrict__ A, const short* __restrict__ Bm,
             const float* __restrict__ bias,
             short* __restrict__ Cb, float* __restrict__ Cf,
             const int* __restrict__ destrow,
             int M, int N, int Kd)
{
    __shared__ short lA[128 * 32];
    __shared__ short lB[128 * 32];
    int nb = N >> 7;
    int bid = blockIdx.x;
    int m0 = (bid / nb) << 7, n0 = (bid % nb) << 7;
    int tid = threadIdx.x;
    int lane = tid & 63, wid = tid >> 6;
    int wm = wid >> 1, wn = wid & 1;
    f32x4 acc[4][4];
    #pragma unroll
    for (int i = 0; i < 4; ++i)
        #pragma unroll
        for (int j2 = 0; j2 < 4; ++j2)
            acc[i][j2] = (f32x4)(0.f);

    const int srow = tid >> 2;
    const int scol = (tid & 3) * 8;
    const short* ga = A + (size_t)(m0 + srow) * Kd + scol;
    const short* gb = Bm + (size_t)(n0 + srow) * Kd + scol;
    short* la0 = &lA[tid * 8];
    short* la1 = &lA[64 * 32 + tid * 8];
    short* lb0 = &lB[tid * 8];
    short* lb1 = &lB[64 * 32 + tid * 8];

    int r = lane & 15, kc = (lane >> 4) * 8;

    for (int k0 = 0; k0 < Kd; k0 += 32) {
        __syncthreads();
        gload16(ga + k0, la0);
        gload16(ga + (size_t)64 * Kd + k0, la1);
        gload16(gb + k0, lb0);
        gload16(gb + (size_t)64 * Kd + k0, lb1);
        __syncthreads();
        short8v af[4], bf[4];
        #pragma unroll
        for (int f = 0; f < 4; ++f)
            af[f] = *(const short8v*)&lA[(wm * 64 + f * 16 + r) * 32 + kc];
        #pragma unroll
        for (int f = 0; f < 4; ++f)
            bf[f] = *(const short8v*)&lB[(wn * 64 + f * 16 + r) * 32 + kc];
        #pragma unroll
        for (int i = 0; i < 4; ++i)
            #pragma unroll
            for (int j2 = 0; j2 < 4; ++j2)
                acc[i][j2] = __builtin_amdgcn_mfma_f32_16x16x32_bf16(
                    af[i], bf[j2], acc[i][j2], 0, 0, 0);
    }

    int cr = (lane >> 4) * 4;
    int cc = lane & 15;
    #pragma unroll
    for (int j2 = 0; j2 < 4; ++j2) {
        int col = n0 + wn * 64 + j2 * 16 + cc;
        float bv = bias[col];
        #pragma unroll
        for (int i = 0; i < 4; ++i) {
            int rowb = m0 + wm * 64 + i * 16 + cr;
            #pragma unroll
            for (int rr = 0; rr < 4; ++rr) {
                float v = acc[i][j2][rr] + bv;
                int row = rowb + rr;
                if (MODE == 0) {
                    Cb[(size_t)row * N + col] = (short)f2b(v);
                } else {
                    int dr = destrow[row];
                    Cf[(size_t)dr * N + col] = v;
                }
            }
        }
    }
}

// ---------- windowed attention v3: deep prefetch, latency-hiding ----------
// 1 block (4 waves) per token; wave wv owns heads 4wv..4wv+3.
// All global loads issued as early as possible into register arrays.
__global__ __launch_bounds__(256)
void attn3_kernel(const short* __restrict__ kvq, const short* __restrict__ bufb,
                  const int* __restrict__ jj, short* __restrict__ o, int T)
{
    __shared__ float ps[16][33];
    int b = blockIdx.x;
    int chunk = gridDim.x >> 3;
    int t = (b & 7) * chunk + (b >> 3);    // XCD-contiguous token chunks
    int tid = threadIdx.x;
    int wv = tid >> 6, lane = tid & 63;
    int j = jj[t];

    // ---- phase-1 lane mapping: (g, c) ----
    int g = lane >> 5, c = lane & 31;
    const short* krow = (j >= c) ? (kvq + (size_t)(t - c) * 2048)
                                 : (bufb + (size_t)(31 + j - c) * 1536);
    const short* qrow = kvq + (size_t)t * 2048 + 1536;
    int h0 = wv * 4 + g;
    int h1 = h0 + 2;

    // issue ALL K/Q fragment loads up front (16 x uint4)
    uint4 kA[4], kB[4], qA[4], qB[4];
    #pragma unroll
    for (int dc = 0; dc < 4; ++dc) {
        kA[dc] = *(const uint4*)(krow + h0 * 32 + dc * 8);
        kB[dc] = *(const uint4*)(krow + h1 * 32 + dc * 8);
        qA[dc] = *(const uint4*)(qrow + h0 * 32 + dc * 8);
        qB[dc] = *(const uint4*)(qrow + h1 * 32 + dc * 8);
    }

    // ---- phase-2 lane mapping: (hl, dq); prefetch first half of V ----
    int hl = lane >> 4, dq = lane & 15;
    int h = wv * 4 + hl;
    int d0 = dq * 4;
    const short* kvrow  = kvq + (size_t)t * 2048 + 512 + h * 64 + d0;
    const short* bufrow = bufb + (size_t)(31 + j) * 1536 + 512 + h * 64 + d0;
    uint2 v0[16], v1[16];
    #pragma unroll
    for (int c2 = 0; c2 < 16; ++c2)
        v0[c2] = *(const uint2*)((j >= c2) ? (kvrow - (size_t)c2 * 2048)
                                           : (bufrow - (size_t)c2 * 1536));

    // ---- phase 1 compute: two logits, dual accumulator chains ----
    float l0a = 0.f, l0b = 0.f, l1a = 0.f, l1b = 0.f;
    #pragma unroll
    for (int dc = 0; dc < 4; ++dc) {
        const unsigned* ka = (const unsigned*)&kA[dc];
        const unsigned* qa = (const unsigned*)&qA[dc];
        const unsigned* kb = (const unsigned*)&kB[dc];
        const unsigned* qb = (const unsigned*)&qB[dc];
        #pragma unroll
        for (int i = 0; i < 4; ++i) {
            l0a = fmaf(blo(ka[i]), blo(qa[i]), l0a);
            l0b = fmaf(bhi(ka[i]), bhi(qa[i]), l0b);
            l1a = fmaf(blo(kb[i]), blo(qb[i]), l1a);
            l1b = fmaf(bhi(kb[i]), bhi(qb[i]), l1b);
        }
    }
    float lg0 = (l0a + l0b) * 0.17677669529663687f;
    float lg1 = (l1a + l1b) * 0.17677669529663687f;
    float m0 = lg0, m1 = lg1;
    #pragma unroll
    for (int mk = 16; mk >= 1; mk >>= 1) {
        m0 = fmaxf(m0, __shfl_xor(m0, mk, 64));
        m1 = fmaxf(m1, __shfl_xor(m1, mk, 64));
    }
    float p0 = __expf(lg0 - m0), p1 = __expf(lg1 - m1);
    float s0 = p0, s1 = p1;
    #pragma unroll
    for (int mk = 16; mk >= 1; mk >>= 1) {
        s0 += __shfl_xor(s0, mk, 64);
        s1 += __shfl_xor(s1, mk, 64);
    }
    ps[h0][c] = p0 / s0;
    ps[h1][c] = p1 / s1;

    // ---- issue second half of V loads ----
    #pragma unroll
    for (int c2 = 16; c2 < 32; ++c2)
        v1[c2 - 16] = *(const uint2*)((j >= c2) ? (kvrow - (size_t)c2 * 2048)
                                                : (bufrow - (size_t)c2 * 1536));

    // ---- phase 2: PV with 4 independent chains ----
    float a0 = 0.f, a1 = 0.f, a2 = 0.f, a3 = 0.f;
    #pragma unroll
    for (int c2 = 0; c2 < 16; ++c2) {
        float pc = ps[h][c2];
        a0 = fmaf(pc, blo(v0[c2].x), a0);
        a1 = fmaf(pc, bhi(v0[c2].x), a1);
        a2 = fmaf(pc, blo(v0[c2].y), a2);
        a3 = fmaf(pc, bhi(v0[c2].y), a3);
    }
    #pragma unroll
    for (int c2 = 16; c2 < 32; ++c2) {
        float pc = ps[h][c2];
        a0 = fmaf(pc, blo(v1[c2 - 16].x), a0);
        a1 = fmaf(pc, bhi(v1[c2 - 16].x), a1);
        a2 = fmaf(pc, blo(v1[c2 - 16].y), a2);
        a3 = fmaf(pc, bhi(v1[c2 - 16].y), a3);
    }
    unsigned w0 = ((unsigned)f2b(a1) << 16) | (unsigned)f2b(a0);
    unsigned w1 = ((unsigned)f2b(a3) << 16) | (unsigned)f2b(a2);
    uint2 ov; ov.x = w0; ov.y = w1;
    *(uint2*)&o[(size_t)t * 1024 + h * 64 + d0] = ov;
}

// ---------- host ----------
extern "C" void kernel_launch(void* const* d_in, const int* in_sizes, int n_in,
                              void* d_out, int out_size, void* d_ws, size_t ws_size,
                              hipStream_t stream)
{
    const float* x      = (const float*)d_in[0];
    const float* Wkv    = (const float*)d_in[1];
    const float* bkv    = (const float*)d_in[2];
    const float* Wq     = (const float*)d_in[3];
    const float* bq     = (const float*)d_in[4];
    const float* Wp     = (const float*)d_in[5];
    const float* bp     = (const float*)d_in[6];
    const float* buffer = (const float*)d_in[7];
    const int*   sl     = (const int*)d_in[8];

    int E  = in_sizes[6];          // 1024
    int Kc = in_sizes[4];          // 512
    int T  = in_sizes[0] / E;      // 4096
    int Bn = in_sizes[8];          // 8
    int EK = E + Kc;               // 1536
    int NKVQ = EK + Kc;            // 2048
    int MAXL = out_size / (Bn * E);

    size_t nX = (size_t)T * E, nWkv = (size_t)EK * E, nWq = (size_t)Kc * E;
    size_t nWp = (size_t)E * E, nBuf = (size_t)in_sizes[7];

    short* xb    = (short*)d_ws;
    short* wkvqb = xb + nX;                 // [EK+Kc, E] contiguous (Wkv rows then Wq rows)
    short* wpb   = wkvqb + nWkv + nWq;
    short* bufb  = wpb + nWp;
    short* kvqb  = bufb + nBuf;             // [T, 2048]: cols 0..1535 kv, 1536..2047 q
    short* ob    = kvqb + (size_t)T * NKVQ;
    int*   jj      = (int*)(ob + (size_t)T * E);
    int*   destrow = jj + T;
    float* biascat = (float*)(destrow + T); // [2048]

    float* y = (float*)d_out;

    long n0 = (long)nX, n1 = n0 + (long)nWkv, n2 = n1 + (long)nWq;
    long n3 = n2 + (long)nWp, n4 = n3 + (long)nBuf;
    int prep_blocks = (int)((n4 / 8 + 255) / 256);
    prep_kernel<<<prep_blocks, 256, 0, stream>>>(
        x, Wkv, Wq, Wp, buffer, sl, bkv, bq, xb, jj, destrow, biascat,
        n0, n1, n2, n3, n4, T, Bn, MAXL, EK, NKVQ);

    // zero only padding rows of y (scatter GEMM writes all real rows)
    padzero_kernel<<<Bn * MAXL, E / 4, 0, stream>>>(y, sl, MAXL, E);

    // merged kv+q projection: [T,1024] @ [2048,1024]^T -> [T,2048]
    gemm_bt<0><<<(T / 128) * (NKVQ / 128), 256, 0, stream>>>(
        xb, wkvqb, biascat, kvqb, nullptr, nullptr, T, NKVQ, E);

    attn3_kernel<<<T, 256, 0, stream>>>(kvqb, bufb, jj, ob, T);

    gemm_bt<1><<<(T / 128) * (E / 128), 256, 0, stream>>>(
        ob, wpb, bp, nullptr, y, destrow, T, E, E);
}

// Round 4
// 90.830 us; speedup vs baseline: 1.5983x; 1.1964x over previous
//
#include <hip/hip_runtime.h>

typedef __attribute__((ext_vector_type(8))) short short8v;
typedef __attribute__((ext_vector_type(4))) float f32x4;

// ---------- helpers ----------
__device__ inline unsigned short f2b(float f) {
    unsigned u = __builtin_bit_cast(unsigned, f);
    unsigned r = u + 0x7fffu + ((u >> 16) & 1u);
    return (unsigned short)(r >> 16);
}
__device__ inline float blo(unsigned u) {
    return __builtin_bit_cast(float, u << 16);
}
__device__ inline float bhi(unsigned u) {
    return __builtin_bit_cast(float, u & 0xffff0000u);
}
__device__ inline void gload16(const void* g, void* l) {
    __builtin_amdgcn_global_load_lds(
        (const __attribute__((address_space(1))) void*)g,
        (__attribute__((address_space(3))) void*)l, 16, 0, 0);
}

// ---------- prep: f32->bf16 conversion + ext prefixes + row maps ----------
__global__ __launch_bounds__(256)
void prep_kernel(const float* __restrict__ x, const float* __restrict__ wkv,
                 const float* __restrict__ wq, const float* __restrict__ wp,
                 const float* __restrict__ buf, const int* __restrict__ sl,
                 const float* __restrict__ bkv, const float* __restrict__ bq,
                 short* __restrict__ dst, short* __restrict__ ext,
                 int* __restrict__ extrow, int* __restrict__ destrow,
                 float* __restrict__ biascat,
                 long n0, long n1, long n2, long n3, long n4,
                 int T, int Bn, int MAXL, int EK, int NKVQ)
{
    long gid = (long)blockIdx.x * blockDim.x + threadIdx.x;
    long e = gid * 8;
    if (e < n3) {
        const float* s; long off;
        if (e < n0)      { s = x;   off = e; }
        else if (e < n1) { s = wkv; off = e - n0; }
        else if (e < n2) { s = wq;  off = e - n1; }
        else             { s = wp;  off = e - n2; }
        float4 a = *(const float4*)(s + off);
        float4 b = *(const float4*)(s + off + 4);
        short8v o;
        o[0] = (short)f2b(a.x); o[1] = (short)f2b(a.y);
        o[2] = (short)f2b(a.z); o[3] = (short)f2b(a.w);
        o[4] = (short)f2b(b.x); o[5] = (short)f2b(b.y);
        o[6] = (short)f2b(b.z); o[7] = (short)f2b(b.w);
        *(short8v*)(dst + e) = o;
    } else if (e < n4) {
        // learned buffer rows -> 31-row prefix of every segment in ext
        long off = e - n3;
        int brow = (int)(off / EK);
        int bcol = (int)(off % EK);
        float4 a = *(const float4*)(buf + off);
        float4 b = *(const float4*)(buf + off + 4);
        short8v o;
        o[0] = (short)f2b(a.x); o[1] = (short)f2b(a.y);
        o[2] = (short)f2b(a.z); o[3] = (short)f2b(a.w);
        o[4] = (short)f2b(b.x); o[5] = (short)f2b(b.y);
        o[6] = (short)f2b(b.z); o[7] = (short)f2b(b.w);
        int start = 0;
        for (int s = 0; s < 8; ++s) {
            int dr = 31 * s + start + brow;
            *(short8v*)&ext[(size_t)dr * EK + bcol] = o;
            start += sl[s];
        }
    }
    if (gid < T) {
        int start = 0, seg = 0, jloc = 0;
        for (int i = 0; i < Bn; ++i) {
            int len = sl[i];
            if (gid >= start && gid < start + len) { seg = i; jloc = (int)gid - start; }
            start += len;
        }
        destrow[gid] = seg * MAXL + jloc;
        extrow[gid]  = 31 * (seg + 1) + (int)gid;
    }
    if (gid < NKVQ) {
        biascat[gid] = (gid < EK) ? bkv[gid] : bq[gid - EK];
    }
}

// ---------- zero only the padding rows of y ----------
__global__ __launch_bounds__(256)
void padzero_kernel(float* __restrict__ y, const int* __restrict__ sl,
                    int MAXL, int E)
{
    int row = blockIdx.x;
    int seg = row / MAXL, pos = row - seg * MAXL;
    if (pos < sl[seg]) return;
    float4 z = {0.f, 0.f, 0.f, 0.f};
    *(float4*)&y[(size_t)row * E + threadIdx.x * 4] = z;
}

// ---------- bf16 GEMM: C[M,N] = A[M,K] @ B[N,K]^T + bias ----------
// MODE 0: split write: col<1536 -> bf16 ext[extrow[row]][col]; else bf16 q[row][col-1536]
// MODE 1: f32 rows scattered: y[rowmap[row]][col]
template<int MODE>
__global__ __launch_bounds__(256)
void gemm_bt(const short* __restrict__ A, const short* __restrict__ Bm,
             const float* __restrict__ bias,
             short* __restrict__ C0, short* __restrict__ C1,
             float* __restrict__ Cf, const int* __restrict__ rowmap,
             int M, int N, int Kd)
{
    __shared__ short lA[128 * 32];
    __shared__ short lB[128 * 32];
    int nb = N >> 7;
    int bid = blockIdx.x;
    int m0 = (bid / nb) << 7, n0 = (bid % nb) << 7;
    int tid = threadIdx.x;
    int lane = tid & 63, wid = tid >> 6;
    int wm = wid >> 1, wn = wid & 1;
    f32x4 acc[4][4];
    #pragma unroll
    for (int i = 0; i < 4; ++i)
        #pragma unroll
        for (int j2 = 0; j2 < 4; ++j2)
            acc[i][j2] = (f32x4)(0.f);

    const int srow = tid >> 2;
    const int scol = (tid & 3) * 8;
    const short* ga = A + (size_t)(m0 + srow) * Kd + scol;
    const short* gb = Bm + (size_t)(n0 + srow) * Kd + scol;
    short* la0 = &lA[tid * 8];
    short* la1 = &lA[64 * 32 + tid * 8];
    short* lb0 = &lB[tid * 8];
    short* lb1 = &lB[64 * 32 + tid * 8];

    int r = lane & 15, kc = (lane >> 4) * 8;

    for (int k0 = 0; k0 < Kd; k0 += 32) {
        __syncthreads();
        gload16(ga + k0, la0);
        gload16(ga + (size_t)64 * Kd + k0, la1);
        gload16(gb + k0, lb0);
        gload16(gb + (size_t)64 * Kd + k0, lb1);
        __syncthreads();
        short8v af[4], bf[4];
        #pragma unroll
        for (int f = 0; f < 4; ++f)
            af[f] = *(const short8v*)&lA[(wm * 64 + f * 16 + r) * 32 + kc];
        #pragma unroll
        for (int f = 0; f < 4; ++f)
            bf[f] = *(const short8v*)&lB[(wn * 64 + f * 16 + r) * 32 + kc];
        #pragma unroll
        for (int i = 0; i < 4; ++i)
            #pragma unroll
            for (int j2 = 0; j2 < 4; ++j2)
                acc[i][j2] = __builtin_amdgcn_mfma_f32_16x16x32_bf16(
                    af[i], bf[j2], acc[i][j2], 0, 0, 0);
    }

    int cr = (lane >> 4) * 4;
    int cc = lane & 15;
    float bv[4];
    #pragma unroll
    for (int j2 = 0; j2 < 4; ++j2)
        bv[j2] = bias[n0 + wn * 64 + j2 * 16 + cc];
    #pragma unroll
    for (int i = 0; i < 4; ++i) {
        #pragma unroll
        for (int rr = 0; rr < 4; ++rr) {
            int row = m0 + wm * 64 + i * 16 + cr + rr;
            int dr = rowmap[row];
            #pragma unroll
            for (int j2 = 0; j2 < 4; ++j2) {
                int col = n0 + wn * 64 + j2 * 16 + cc;
                float v = acc[i][j2][rr] + bv[j2];
                if (MODE == 0) {
                    if (col < 1536)
                        C0[(size_t)dr * 1536 + col] = (short)f2b(v);
                    else
                        C1[(size_t)row * 512 + (col - 1536)] = (short)f2b(v);
                } else {
                    Cf[(size_t)dr * N + col] = v;
                }
            }
        }
    }
}

// ---------- windowed attention v4: ext layout + LDS staging ----------
// Block = 16 tokens x 4 heads (4 waves, wave = 1 head).
// Stage ext rows r0..r0+46 (47 rows, K 128 cols + V 256 cols) into LDS,
// coalesced. All compute reads from LDS. Window is always exactly 32 keys
// (learned prefix rows make it dense) -> no masks, no source select.
__global__ __launch_bounds__(256)
void attn4_kernel(const short* __restrict__ ext, const short* __restrict__ qb,
                  const int* __restrict__ extrow, short* __restrict__ o)
{
    __shared__ short lK[48 * 136];   // rows padded 128->136
    __shared__ short lV[48 * 264];   // rows padded 256->264
    __shared__ float ps[4][16][33];

    int bid = blockIdx.x;
    int swz = (bid & 7) * (gridDim.x >> 3) + (bid >> 3);  // XCD-contiguous
    int tg = swz >> 2, hg = swz & 3;
    int t0 = tg << 4, h0 = hg << 2;
    int r0 = extrow[t0] - 31;
    int tid = threadIdx.x;

    // ---- stage K: 47 rows x 128 cols ----
    #pragma unroll
    for (int p = 0; p < 3; ++p) {
        int idx = p * 2048 + tid * 8;
        int row = idx >> 7, col = idx & 127;
        int sr = r0 + (row < 47 ? row : 46);
        *(short8v*)&lK[row * 136 + col] =
            *(const short8v*)&ext[(size_t)sr * 1536 + h0 * 32 + col];
    }
    // ---- stage V: 47 rows x 256 cols ----
    #pragma unroll
    for (int p = 0; p < 6; ++p) {
        int idx = p * 2048 + tid * 8;
        int row = idx >> 8, col = idx & 255;
        int sr = r0 + (row < 47 ? row : 46);
        *(short8v*)&lV[row * 264 + col] =
            *(const short8v*)&ext[(size_t)sr * 1536 + 512 + h0 * 64 + col];
    }

    int wv = tid >> 6, lane = tid & 63;
    int ti = lane >> 2, q4 = lane & 3;
    int t = t0 + ti, h = h0 + wv;

    // Q into registers (issued before the barrier to hide latency)
    const short* qp = qb + (size_t)t * 512 + h * 32;
    uint4 qv0 = *(const uint4*)(qp);
    uint4 qv1 = *(const uint4*)(qp + 8);
    uint4 qv2 = *(const uint4*)(qp + 16);
    uint4 qv3 = *(const uint4*)(qp + 24);

    __syncthreads();

    // ---- QK: each lane does 8 window positions c = q4 + 4i ----
    float lg[8];
    #pragma unroll
    for (int i = 0; i < 8; ++i) {
        int c = q4 + i * 4;
        int lr = ti + 31 - c;
        const short* kr = &lK[lr * 136 + wv * 32];
        uint4 kv0 = *(const uint4*)(kr);
        uint4 kv1 = *(const uint4*)(kr + 8);
        uint4 kv2 = *(const uint4*)(kr + 16);
        uint4 kv3 = *(const uint4*)(kr + 24);
        float a0 = 0.f, a1 = 0.f;
        const unsigned* ka = (const unsigned*)&kv0;
        const unsigned* qa = (const unsigned*)&qv0;
        // kv0..kv3 and qv0..qv3 are contiguous uint4 locals; walk as arrays
        uint4 kk[4] = {kv0, kv1, kv2, kv3};
        uint4 qq[4] = {qv0, qv1, qv2, qv3};
        #pragma unroll
        for (int w = 0; w < 4; ++w) {
            a0 = fmaf(blo(kk[w].x), blo(qq[w].x), a0);
            a1 = fmaf(bhi(kk[w].x), bhi(qq[w].x), a1);
            a0 = fmaf(blo(kk[w].y), blo(qq[w].y), a0);
            a1 = fmaf(bhi(kk[w].y), bhi(qq[w].y), a1);
            a0 = fmaf(blo(kk[w].z), blo(qq[w].z), a0);
            a1 = fmaf(bhi(kk[w].z), bhi(qq[w].z), a1);
            a0 = fmaf(blo(kk[w].w), blo(qq[w].w), a0);
            a1 = fmaf(bhi(kk[w].w), bhi(qq[w].w), a1);
        }
        (void)ka; (void)qa;
        lg[i] = (a0 + a1) * 0.17677669529663687f;
    }
    // softmax across 32 = 8 local x 4 lanes (q4 group)
    float m = lg[0];
    #pragma unroll
    for (int i = 1; i < 8; ++i) m = fmaxf(m, lg[i]);
    m = fmaxf(m, __shfl_xor(m, 1, 64));
    m = fmaxf(m, __shfl_xor(m, 2, 64));
    float s = 0.f;
    float pv[8];
    #pragma unroll
    for (int i = 0; i < 8; ++i) { pv[i] = __expf(lg[i] - m); s += pv[i]; }
    s += __shfl_xor(s, 1, 64);
    s += __shfl_xor(s, 2, 64);
    float inv = 1.f / s;
    #pragma unroll
    for (int i = 0; i < 8; ++i)
        ps[wv][ti][q4 + i * 4] = pv[i] * inv;

    __syncthreads();

    // ---- PV: lane (ti, q4) owns dv chunk q4*16 ----
    int dv0 = q4 * 16;
    float a[16];
    #pragma unroll
    for (int k = 0; k < 16; ++k) a[k] = 0.f;
    #pragma unroll
    for (int c = 0; c < 32; ++c) {
        int lr = ti + 31 - c;
        float pc = ps[wv][ti][c];
        const short* vr = &lV[lr * 264 + wv * 64 + dv0];
        uint4 v0 = *(const uint4*)(vr);
        uint4 v1 = *(const uint4*)(vr + 8);
        a[0]  = fmaf(pc, blo(v0.x), a[0]);
        a[1]  = fmaf(pc, bhi(v0.x), a[1]);
        a[2]  = fmaf(pc, blo(v0.y), a[2]);
        a[3]  = fmaf(pc, bhi(v0.y), a[3]);
        a[4]  = fmaf(pc, blo(v0.z), a[4]);
        a[5]  = fmaf(pc, bhi(v0.z), a[5]);
        a[6]  = fmaf(pc, blo(v0.w), a[6]);
        a[7]  = fmaf(pc, bhi(v0.w), a[7]);
        a[8]  = fmaf(pc, blo(v1.x), a[8]);
        a[9]  = fmaf(pc, bhi(v1.x), a[9]);
        a[10] = fmaf(pc, blo(v1.y), a[10]);
        a[11] = fmaf(pc, bhi(v1.y), a[11]);
        a[12] = fmaf(pc, blo(v1.z), a[12]);
        a[13] = fmaf(pc, bhi(v1.z), a[13]);
        a[14] = fmaf(pc, blo(v1.w), a[14]);
        a[15] = fmaf(pc, bhi(v1.w), a[15]);
    }
    unsigned ow[8];
    #pragma unroll
    for (int k = 0; k < 8; ++k)
        ow[k] = ((unsigned)f2b(a[2 * k + 1]) << 16) | (unsigned)f2b(a[2 * k]);
    short* op = o + (size_t)t * 1024 + h * 64 + dv0;
    uint4 s0 = {ow[0], ow[1], ow[2], ow[3]};
    uint4 s1 = {ow[4], ow[5], ow[6], ow[7]};
    *(uint4*)(op)     = s0;
    *(uint4*)(op + 8) = s1;
}

// ---------- host ----------
extern "C" void kernel_launch(void* const* d_in, const int* in_sizes, int n_in,
                              void* d_out, int out_size, void* d_ws, size_t ws_size,
                              hipStream_t stream)
{
    const float* x      = (const float*)d_in[0];
    const float* Wkv    = (const float*)d_in[1];
    const float* bkv    = (const float*)d_in[2];
    const float* Wq     = (const float*)d_in[3];
    const float* bq     = (const float*)d_in[4];
    const float* Wp     = (const float*)d_in[5];
    const float* bp     = (const float*)d_in[6];
    const float* buffer = (const float*)d_in[7];
    const int*   sl     = (const int*)d_in[8];

    int E  = in_sizes[6];          // 1024
    int Kc = in_sizes[4];          // 512
    int T  = in_sizes[0] / E;      // 4096
    int Bn = in_sizes[8];          // 8
    int EK = E + Kc;               // 1536
    int NKVQ = EK + Kc;            // 2048
    int MAXL = out_size / (Bn * E);
    int TEXT = T + 31 * Bn;        // 4344 ext rows

    size_t nX = (size_t)T * E, nWkv = (size_t)EK * E, nWq = (size_t)Kc * E;
    size_t nWp = (size_t)E * E, nBuf = (size_t)in_sizes[7];

    short* xb    = (short*)d_ws;
    short* wkvqb = xb + nX;                 // [2048,1024] merged weights
    short* wpb   = wkvqb + nWkv + nWq;
    short* qbuf  = wpb + nWp;               // [T,512]
    short* extb  = qbuf + (size_t)T * Kc;   // [TEXT,1536]
    short* ob    = extb + (size_t)TEXT * EK;
    int*   extrowp = (int*)(ob + (size_t)T * E);
    int*   destrow = extrowp + T;
    float* biascat = (float*)(destrow + T);

    float* y = (float*)d_out;

    long n0 = (long)nX, n1 = n0 + (long)nWkv, n2 = n1 + (long)nWq;
    long n3 = n2 + (long)nWp, n4 = n3 + (long)nBuf;
    int prep_blocks = (int)((n4 / 8 + 255) / 256);
    prep_kernel<<<prep_blocks, 256, 0, stream>>>(
        x, Wkv, Wq, Wp, buffer, sl, bkv, bq, xb, extb,
        extrowp, destrow, biascat,
        n0, n1, n2, n3, n4, T, Bn, MAXL, EK, NKVQ);

    padzero_kernel<<<Bn * MAXL, E / 4, 0, stream>>>(y, sl, MAXL, E);

    // merged kv+q projection; kv rows scatter into ext layout, q separate
    gemm_bt<0><<<(T / 128) * (NKVQ / 128), 256, 0, stream>>>(
        xb, wkvqb, biascat, extb, qbuf, nullptr, extrowp, T, NKVQ, E);

    attn4_kernel<<<(T / 16) * 4, 256, 0, stream>>>(extb, qbuf, extrowp, ob);

    gemm_bt<1><<<(T / 128) * (E / 128), 256, 0, stream>>>(
        ob, wpb, bp, nullptr, nullptr, y, destrow, T, E, E);
}